// Round 9
// baseline (158.889 us; speedup 1.0000x reference)
//
#include <hip/hip_runtime.h>
#include <hip/hip_bf16.h>
#include <math.h>

// FeedForwardQuantum — Round 15: round-8 fused + B-operand moved OUT of LDS.
// Theory: at 53.6us the LDS pipe is saturated (A+B ds_reads + HWRITE + DMA
// ≈ 1090cyc/block-chunk x 2 blocks ≈ the whole 2010cyc budget). w2b is 2MiB
// = L2-resident, so B-frags are loaded straight from global into registers
// (double-buffered one chunk ahead; quads give contiguous 64B runs per row).
// Deletes STAGEB + all B ds_reads: LDS/block-chunk ~1090 -> ~576 cyc.
// A path (HCALC/HWRITE/A-read swizzle pair), Z/q prologue, epilogue:
// verbatim round-8 (harness-verified, absmax 0.00390625). Same B values,
// same MFMA order -> bit-identical output.

typedef __attribute__((ext_vector_type(8))) short short8;
typedef __attribute__((ext_vector_type(8))) unsigned short ushort8;
typedef __attribute__((ext_vector_type(4))) float fx4;

constexpr int EDIM = 512;
constexpr int FDIM = 2048;
constexpr int NQ   = 10;
constexpr int BK   = 64;
constexpr int BM   = 128;
constexpr int BN   = 128;

__device__ __forceinline__ ushort f2bf(float f) {   // f32 -> bf16 RNE
    union { float f; unsigned u; } v; v.f = f;
    unsigned u = v.u + 0x7FFFu + ((v.u >> 16) & 1u);
    return (ushort)(u >> 16);
}
__device__ __forceinline__ float bf2f(ushort u) {
    union { unsigned u; float f; } v; v.u = (unsigned)u << 16; return v.f;
}
// HW packed f32x2 -> bf16x2, RNE (bit-identical to manual f2bf pair)
__device__ __forceinline__ unsigned cvtpk(float lo, float hi) {
    unsigned r;
    asm("v_cvt_pk_bf16_f32 %0, %1, %2" : "=v"(r) : "v"(lo), "v"(hi));
    return r;
}

// ---- prep: w2 f32->bf16 + split-precision w1t build (verbatim round-6) ----
__global__ void prep(const float* __restrict__ w2, const float* __restrict__ w1,
                     const float* __restrict__ b1,
                     ushort* __restrict__ w2b, ushort* __restrict__ w1t) {
    int gid = blockIdx.x * blockDim.x + threadIdx.x;
    int np  = gridDim.x * blockDim.x;
    for (int i = gid; i < EDIM * FDIM / 4; i += np) {
        float4 v = ((const float4*)w2)[i];
        ushort4 o; o.x = f2bf(v.x); o.y = f2bf(v.y); o.z = f2bf(v.z); o.w = f2bf(v.w);
        ((ushort4*)w2b)[i] = o;
    }
    for (int f = gid; f < FDIM; f += np) {
        ushort zr[32];
        #pragma unroll
        for (int w = 0; w < NQ; ++w) {
            float v  = w1[f * NQ + w];
            ushort hb = f2bf(v);
            ushort lb = f2bf(v - bf2f(hb));
            zr[w] = hb; zr[10 + w] = hb; zr[20 + w] = lb;
        }
        float bv  = b1[f];
        ushort bh = f2bf(bv);
        zr[30] = bh; zr[31] = f2bf(bv - bf2f(bh));
        #pragma unroll
        for (int u = 0; u < 4; ++u)
            *(ushort8*)&w1t[f * 32 + u * 8] = *(ushort8*)&zr[u * 8];
    }
}

// ---- fused: out = relu(q@w1^T+b1) @ w2^T + b2 ----
__global__ __launch_bounds__(256, 2) void fused(
    const float* __restrict__ x, const float* __restrict__ rx,
    const ushort* __restrict__ w1t,   // [FDIM][32] bf16 split-precision
    const ushort* __restrict__ w2b,   // [EDIM][FDIM] bf16
    const float* __restrict__ b2,
    float* __restrict__ out)
{
    __shared__ __align__(16) ushort Zs[BM * 32];       // 8 KiB
    __shared__ __align__(16) ushort As[2][BM * BK];    // 32 KiB (h tiles)

    const int tid = threadIdx.x;
    const int m0  = blockIdx.x * BM;
    const int n0  = blockIdx.y * BN;

    // ---- q prologue (verbatim) -> split bf16 Z rows ----
    if (tid < BM) {
        const float* xr = x + (size_t)(m0 + tid) * EDIM;
        float4 xa = *(const float4*)xr;
        float4 xb = *(const float4*)(xr + 4);
        float2 xc = *(const float2*)(xr + 8);
        float xv[NQ] = {xa.x, xa.y, xa.z, xa.w, xb.x, xb.y, xb.z, xb.w, xc.x, xc.y};
        float c[NQ], q[NQ];
        #pragma unroll
        for (int w = 0; w < NQ; ++w) c[w] = cosf(xv[w] + rx[w]);
        float p0 = c[1];
        #pragma unroll
        for (int w = 2; w < NQ; ++w) p0 *= c[w];
        q[0] = p0;
        float p = c[0];
        #pragma unroll
        for (int w = 1; w < NQ; ++w) { p *= c[w]; q[w] = p; }
        ushort zr[32];
        #pragma unroll
        for (int w = 0; w < NQ; ++w) {
            ushort hb = f2bf(q[w]);
            ushort lb = f2bf(q[w] - bf2f(hb));
            zr[w] = hb; zr[10 + w] = lb; zr[20 + w] = hb;
        }
        zr[30] = 0x3F80u; zr[31] = 0x3F80u;   // 1.0, 1.0
        #pragma unroll
        for (int u = 0; u < 4; ++u)
            *(ushort8*)&Zs[tid * 32 + u * 8] = *(ushort8*)&zr[u * 8];
    }
    __syncthreads();

    const int wave = tid >> 6, lane = tid & 63;
    const int quad = lane >> 4, l16 = lane & 15;
    const int wm   = wave >> 1, wn = wave & 1;
    const int swz  = l16 & 7;

    // H-production roles (verbatim round-6/7/8)
    const int hm0 = (wave & 1) * 64;
    const int hf0 = (wave >> 1) * 32;
    short8 zf[4];
    #pragma unroll
    for (int mi = 0; mi < 4; ++mi)
        zf[mi] = *(const short8*)&Zs[(hm0 + mi * 16 + l16) * 32 + quad * 8];

    // B-frag global pointers: row = n0 + wn*64 + nt*16 + l16; k-block hf*4+quad
    // (same logical elements the old LDS path delivered — swizzle not needed
    //  for global reads). Advance BK per chunk.
    const ushort* gBF[4];
    #pragma unroll
    for (int nt = 0; nt < 4; ++nt)
        gBF[nt] = w2b + (size_t)(n0 + wn * 64 + nt * 16 + l16) * FDIM + quad * 8;

    // A fragment-read offsets (verbatim)
    int aro[4];
    #pragma unroll
    for (int t = 0; t < 4; ++t)
        aro[t] = (wm * 64 + t * 16 + l16) * BK;

    fx4 acc[4][4];
    #pragma unroll
    for (int a = 0; a < 4; ++a)
        #pragma unroll
        for (int b = 0; b < 4; ++b) acc[a][b] = fx4{0.f, 0.f, 0.f, 0.f};

    const fx4 zacc = fx4{0.f, 0.f, 0.f, 0.f};

    short8 wfE[2], wfO[2];
    uint2  pE[4][2], pO[4][2];
    short8 bfE[4][2], bfO[4][2];    // B-frag double buffer (registers)

#define WLOAD(WF, CH) do { _Pragma("unroll") \
    for (int fi = 0; fi < 2; ++fi) \
        WF[fi] = *(const short8*)(w1t + ((CH) * 64 + hf0 + fi * 16 + l16) * 32 + quad * 8); \
} while (0)

// load one chunk's B-frags straight from global (L2-hit) and advance
#define BLOAD(BFR) do { _Pragma("unroll") \
    for (int nt = 0; nt < 4; ++nt) { \
        BFR[nt][0] = *(const short8*)(gBF[nt]); \
        BFR[nt][1] = *(const short8*)(gBF[nt] + 32); \
        gBF[nt] += BK; \
    } \
} while (0)

// h mfma + relu + HW cvt_pk bf16 pack into registers P (no LDS write)
#define HCALC(P, WF) do { _Pragma("unroll") \
    for (int mi = 0; mi < 4; ++mi) \
        _Pragma("unroll") \
        for (int fi = 0; fi < 2; ++fi) { \
            fx4 hv = __builtin_amdgcn_mfma_f32_16x16x32_bf16( \
                WF[fi], zf[mi], zacc, 0, 0, 0); \
            unsigned ua = cvtpk(fmaxf(hv[0], 0.f), fmaxf(hv[1], 0.f)); \
            unsigned ub = cvtpk(fmaxf(hv[2], 0.f), fmaxf(hv[3], 0.f)); \
            P[mi][fi] = make_uint2(ua, ub); \
        } \
} while (0)

// write previously packed h tile into As[BUF] (addresses verbatim)
#define HWRITE(BUF, P) do { _Pragma("unroll") \
    for (int mi = 0; mi < 4; ++mi) { \
        const int hrow = hm0 + mi * 16 + l16; \
        ushort* arow = &As[BUF][hrow * BK]; \
        _Pragma("unroll") \
        for (int fi = 0; fi < 2; ++fi) { \
            const int blk = (hf0 >> 3) + fi * 2 + (quad >> 1); \
            *(uint2*)&arow[((blk ^ swz) << 3) + ((quad & 1) << 2)] = P[mi][fi]; \
        } \
    } \
} while (0)

// A from LDS (8 ds_read_b128), B from registers; MFMA order verbatim
#define COMPUTE(BUF, BFR) do { \
    short8 af[4][2]; \
    _Pragma("unroll") \
    for (int t = 0; t < 4; ++t) \
        _Pragma("unroll") \
        for (int hf = 0; hf < 2; ++hf) \
            af[t][hf] = *(const short8*)&As[BUF][aro[t] + (((hf * 4 + quad) ^ swz) << 3)]; \
    __builtin_amdgcn_s_setprio(1); \
    _Pragma("unroll") \
    for (int hf = 0; hf < 2; ++hf) \
        _Pragma("unroll") \
        for (int mt = 0; mt < 4; ++mt) \
            _Pragma("unroll") \
            for (int nt = 0; nt < 4; ++nt) \
                acc[mt][nt] = __builtin_amdgcn_mfma_f32_16x16x32_bf16( \
                    af[mt][hf], BFR[nt][hf], acc[mt][nt], 0, 0, 0); \
    __builtin_amdgcn_s_setprio(0); \
} while (0)

    // ---- prologue: As[0]=h(0); pO=pack(1); wf->w(2),w(3); bfE=B(0) ----
    WLOAD(wfE, 0); WLOAD(wfO, 1);
    BLOAD(bfE);                       // chunk 0
    HCALC(pE, wfE); HWRITE(0, pE);
    HCALC(pO, wfO);
    WLOAD(wfE, 2); WLOAD(wfO, 3);
    __syncthreads();

    // ---- pairs p=0..13 ----
    for (int p = 0; p < 14; ++p) {
        BLOAD(bfO);                                   // B(2p+1)
        HWRITE(1, pO); HCALC(pE, wfE); WLOAD(wfE, 2 * p + 4);
        COMPUTE(0, bfE);                              // chunk 2p
        __syncthreads();
        BLOAD(bfE);                                   // B(2p+2)
        HWRITE(0, pE); HCALC(pO, wfO); WLOAD(wfO, 2 * p + 5);
        COMPUTE(1, bfO);                              // chunk 2p+1
        __syncthreads();
    }
    // ---- pair 14: chunks 28,29 (no wloads) ----
    BLOAD(bfO);                                       // B(29)
    HWRITE(1, pO); HCALC(pE, wfE);
    COMPUTE(0, bfE); __syncthreads();                 // chunk 28
    BLOAD(bfE);                                       // B(30)
    HWRITE(0, pE); HCALC(pO, wfO);
    COMPUTE(1, bfO); __syncthreads();                 // chunk 29
    // ---- tail: chunks 30,31 ----
    BLOAD(bfO);                                       // B(31)
    HWRITE(1, pO);
    COMPUTE(0, bfE); __syncthreads();                 // chunk 30
    COMPUTE(1, bfO);                                  // chunk 31

#undef COMPUTE
#undef HWRITE
#undef HCALC
#undef BLOAD
#undef WLOAD

    // ---- epilogue: + b2 (verbatim, harness-verified layout) ----
    float bb[4];
    #pragma unroll
    for (int nt = 0; nt < 4; ++nt) bb[nt] = b2[n0 + wn * 64 + nt * 16 + l16];
    #pragma unroll
    for (int mt = 0; mt < 4; ++mt) {
        const int mbase = m0 + wm * 64 + mt * 16 + quad * 4;
        #pragma unroll
        for (int nt = 0; nt < 4; ++nt) {
            const int n = n0 + wn * 64 + nt * 16 + l16;
            #pragma unroll
            for (int r = 0; r < 4; ++r)
                out[(size_t)(mbase + r) * EDIM + n] = acc[mt][nt][r] + bb[nt];
        }
    }
}

extern "C" void kernel_launch(void* const* d_in, const int* in_sizes, int n_in,
                              void* d_out, int out_size, void* d_ws, size_t ws_size,
                              hipStream_t stream) {
    const float* x  = (const float*)d_in[0];
    const float* rx = (const float*)d_in[1];
    const float* w1 = (const float*)d_in[2];
    const float* b1 = (const float*)d_in[3];
    const float* w2 = (const float*)d_in[4];
    const float* b2 = (const float*)d_in[5];
    float* out = (float*)d_out;

    const int M = in_sizes[0] / EDIM;   // 16384

    ushort* w2b = (ushort*)d_ws;                                    // 2 MiB
    ushort* w1t = (ushort*)((char*)d_ws + (size_t)EDIM * FDIM * 2); // 128 KiB
    (void)ws_size; (void)n_in; (void)out_size;

    hipLaunchKernelGGL(prep, dim3(256), dim3(256), 0, stream, w2, w1, b1, w2b, w1t);
    hipLaunchKernelGGL(fused, dim3(M / BM, EDIM / BN), dim3(256), 0, stream,
                       x, rx, w1t, w2b, b2, out);
}

// Round 11
// 129.271 us; speedup vs baseline: 1.2291x; 1.2291x over previous
//
#include <hip/hip_runtime.h>
#include <hip/hip_bf16.h>
#include <math.h>

// FeedForwardQuantum — Round 17: round-16 with the prep OOB fixed (loop bound
// was 262144 units = 2x the real 131072 = EDIM*FDIM/8; ng>=4 read 4MiB past
// w2 -> core dump, and clobbered w1t). Design unchanged:
// B out of LDS via pre-swizzled fragment-ordered w2p (coalesced 1KB wave
// loads, L2-resident); A path (HCALC/HWRITE/A-read swizzle), Z/q prologue,
// epilogue verbatim round-8 (harness-verified). Same bf16 values + same MFMA
// order -> absmax 0.00390625 expected.

typedef __attribute__((ext_vector_type(8))) short short8;
typedef __attribute__((ext_vector_type(8))) unsigned short ushort8;
typedef __attribute__((ext_vector_type(4))) float fx4;

constexpr int EDIM = 512;
constexpr int FDIM = 2048;
constexpr int NQ   = 10;
constexpr int BK   = 64;
constexpr int BM   = 128;
constexpr int BN   = 128;
constexpr int CSTR = 8192;        // w2p elements per chunk (per ng)
constexpr int NGSTR = 262144;     // w2p elements per ng (32 chunks)
constexpr int W2P_UNITS = EDIM * FDIM / 8;   // 131072 — the round-16 bug was 2x this

__device__ __forceinline__ ushort f2bf(float f) {   // f32 -> bf16 RNE
    union { float f; unsigned u; } v; v.f = f;
    unsigned u = v.u + 0x7FFFu + ((v.u >> 16) & 1u);
    return (ushort)(u >> 16);
}
__device__ __forceinline__ float bf2f(ushort u) {
    union { unsigned u; float f; } v; v.u = (unsigned)u << 16; return v.f;
}
// HW packed f32x2 -> bf16x2, RNE (bit-identical to manual f2bf pair)
__device__ __forceinline__ unsigned cvtpk(float lo, float hi) {
    unsigned r;
    asm("v_cvt_pk_bf16_f32 %0, %1, %2" : "=v"(r) : "v"(lo), "v"(hi));
    return r;
}

// ---- prep: w2 -> w2p (fragment-ordered) + split-precision w1t ----
__global__ void prep(const float* __restrict__ w2, const float* __restrict__ w1,
                     const float* __restrict__ b1,
                     ushort* __restrict__ w2p, ushort* __restrict__ w1t) {
    int gid = blockIdx.x * blockDim.x + threadIdx.x;
    int np  = gridDim.x * blockDim.x;
    // w2p: unit u = 8 elements. u = ((((ng*32+c)*2+wn)*4+nt)*2+hf)*64 + quad*16 + l16
    for (int u = gid; u < W2P_UNITS; u += np) {
        int l16 = u & 15, quad = (u >> 4) & 3, hf = (u >> 6) & 1;
        int nt = (u >> 7) & 3, wn = (u >> 9) & 1, c = (u >> 10) & 31, ng = u >> 15;
        int row = ng * 128 + wn * 64 + nt * 16 + l16;
        int col = c * 64 + (hf * 4 + quad) * 8;
        const float* src = w2 + (size_t)row * FDIM + col;
        float4 a = *(const float4*)src;
        float4 b = *(const float4*)(src + 4);
        ushort8 o;
        o[0] = f2bf(a.x); o[1] = f2bf(a.y); o[2] = f2bf(a.z); o[3] = f2bf(a.w);
        o[4] = f2bf(b.x); o[5] = f2bf(b.y); o[6] = f2bf(b.z); o[7] = f2bf(b.w);
        *(ushort8*)&w2p[(size_t)u * 8] = o;
    }
    // w1t (verbatim round-6)
    for (int f = gid; f < FDIM; f += np) {
        ushort zr[32];
        #pragma unroll
        for (int w = 0; w < NQ; ++w) {
            float v  = w1[f * NQ + w];
            ushort hb = f2bf(v);
            ushort lb = f2bf(v - bf2f(hb));
            zr[w] = hb; zr[10 + w] = hb; zr[20 + w] = lb;
        }
        float bv  = b1[f];
        ushort bh = f2bf(bv);
        zr[30] = bh; zr[31] = f2bf(bv - bf2f(bh));
        #pragma unroll
        for (int u = 0; u < 4; ++u)
            *(ushort8*)&w1t[f * 32 + u * 8] = *(ushort8*)&zr[u * 8];
    }
}

// ---- fused: out = relu(q@w1^T+b1) @ w2^T + b2 ----
__global__ __launch_bounds__(256, 2) void fused(
    const float* __restrict__ x, const float* __restrict__ rx,
    const ushort* __restrict__ w1t,   // [FDIM][32] bf16 split-precision
    const ushort* __restrict__ w2p,   // fragment-ordered w2 bf16
    const float* __restrict__ b2,
    float* __restrict__ out)
{
    __shared__ __align__(16) ushort Zs[BM * 32];       // 8 KiB
    __shared__ __align__(16) ushort As[2][BM * BK];    // 32 KiB (h tiles)

    const int tid = threadIdx.x;
    const int m0  = blockIdx.x * BM;
    const int n0  = blockIdx.y * BN;

    // ---- q prologue (verbatim) -> split bf16 Z rows ----
    if (tid < BM) {
        const float* xr = x + (size_t)(m0 + tid) * EDIM;
        float4 xa = *(const float4*)xr;
        float4 xb = *(const float4*)(xr + 4);
        float2 xc = *(const float2*)(xr + 8);
        float xv[NQ] = {xa.x, xa.y, xa.z, xa.w, xb.x, xb.y, xb.z, xb.w, xc.x, xc.y};
        float c[NQ], q[NQ];
        #pragma unroll
        for (int w = 0; w < NQ; ++w) c[w] = cosf(xv[w] + rx[w]);
        float p0 = c[1];
        #pragma unroll
        for (int w = 2; w < NQ; ++w) p0 *= c[w];
        q[0] = p0;
        float p = c[0];
        #pragma unroll
        for (int w = 1; w < NQ; ++w) { p *= c[w]; q[w] = p; }
        ushort zr[32];
        #pragma unroll
        for (int w = 0; w < NQ; ++w) {
            ushort hb = f2bf(q[w]);
            ushort lb = f2bf(q[w] - bf2f(hb));
            zr[w] = hb; zr[10 + w] = lb; zr[20 + w] = hb;
        }
        zr[30] = 0x3F80u; zr[31] = 0x3F80u;   // 1.0, 1.0
        #pragma unroll
        for (int u = 0; u < 4; ++u)
            *(ushort8*)&Zs[tid * 32 + u * 8] = *(ushort8*)&zr[u * 8];
    }
    __syncthreads();

    const int wave = tid >> 6, lane = tid & 63;
    const int quad = lane >> 4, l16 = lane & 15;
    const int wm   = wave >> 1, wn = wave & 1;
    const int swz  = l16 & 7;

    // H-production roles (verbatim round-6/7/8)
    const int hm0 = (wave & 1) * 64;
    const int hf0 = (wave >> 1) * 32;
    short8 zf[4];
    #pragma unroll
    for (int mi = 0; mi < 4; ++mi)
        zf[mi] = *(const short8*)&Zs[(hm0 + mi * 16 + l16) * 32 + quad * 8];

    // B: coalesced fragment loads from pre-swizzled w2p (L2-resident).
    const ushort* gB = w2p + (size_t)blockIdx.y * NGSTR + wn * 4096 + lane * 8;

    // A fragment-read offsets (verbatim)
    int aro[4];
    #pragma unroll
    for (int t = 0; t < 4; ++t)
        aro[t] = (wm * 64 + t * 16 + l16) * BK;

    fx4 acc[4][4];
    #pragma unroll
    for (int a = 0; a < 4; ++a)
        #pragma unroll
        for (int b = 0; b < 4; ++b) acc[a][b] = fx4{0.f, 0.f, 0.f, 0.f};

    const fx4 zacc = fx4{0.f, 0.f, 0.f, 0.f};

    short8 wfE[2], wfO[2];
    uint2  pE[4][2], pO[4][2];
    short8 bfE[4][2], bfO[4][2];    // B-frag double buffer (registers)

#define WLOAD(WF, CH) do { _Pragma("unroll") \
    for (int fi = 0; fi < 2; ++fi) \
        WF[fi] = *(const short8*)(w1t + ((CH) * 64 + hf0 + fi * 16 + l16) * 32 + quad * 8); \
} while (0)

// one chunk's B-frags: 8 wave-coalesced 1KB loads; advance to next chunk
#define BLOAD(BFR) do { _Pragma("unroll") \
    for (int nt = 0; nt < 4; ++nt) { \
        BFR[nt][0] = *(const short8*)(gB + nt * 1024); \
        BFR[nt][1] = *(const short8*)(gB + nt * 1024 + 512); \
    } \
    gB += CSTR; \
} while (0)

// h mfma + relu + HW cvt_pk bf16 pack into registers P (no LDS write)
#define HCALC(P, WF) do { _Pragma("unroll") \
    for (int mi = 0; mi < 4; ++mi) \
        _Pragma("unroll") \
        for (int fi = 0; fi < 2; ++fi) { \
            fx4 hv = __builtin_amdgcn_mfma_f32_16x16x32_bf16( \
                WF[fi], zf[mi], zacc, 0, 0, 0); \
            unsigned ua = cvtpk(fmaxf(hv[0], 0.f), fmaxf(hv[1], 0.f)); \
            unsigned ub = cvtpk(fmaxf(hv[2], 0.f), fmaxf(hv[3], 0.f)); \
            P[mi][fi] = make_uint2(ua, ub); \
        } \
} while (0)

// write previously packed h tile into As[BUF] (addresses verbatim)
#define HWRITE(BUF, P) do { _Pragma("unroll") \
    for (int mi = 0; mi < 4; ++mi) { \
        const int hrow = hm0 + mi * 16 + l16; \
        ushort* arow = &As[BUF][hrow * BK]; \
        _Pragma("unroll") \
        for (int fi = 0; fi < 2; ++fi) { \
            const int blk = (hf0 >> 3) + fi * 2 + (quad >> 1); \
            *(uint2*)&arow[((blk ^ swz) << 3) + ((quad & 1) << 2)] = P[mi][fi]; \
        } \
    } \
} while (0)

// A from LDS (8 ds_read_b128), B from registers; MFMA order verbatim
#define COMPUTE(BUF, BFR) do { \
    short8 af[4][2]; \
    _Pragma("unroll") \
    for (int t = 0; t < 4; ++t) \
        _Pragma("unroll") \
        for (int hf = 0; hf < 2; ++hf) \
            af[t][hf] = *(const short8*)&As[BUF][aro[t] + (((hf * 4 + quad) ^ swz) << 3)]; \
    __builtin_amdgcn_s_setprio(1); \
    _Pragma("unroll") \
    for (int hf = 0; hf < 2; ++hf) \
        _Pragma("unroll") \
        for (int mt = 0; mt < 4; ++mt) \
            _Pragma("unroll") \
            for (int nt = 0; nt < 4; ++nt) \
                acc[mt][nt] = __builtin_amdgcn_mfma_f32_16x16x32_bf16( \
                    af[mt][hf], BFR[nt][hf], acc[mt][nt], 0, 0, 0); \
    __builtin_amdgcn_s_setprio(0); \
} while (0)

    // ---- prologue: As[0]=h(0); pO=pack(1); wf->w(2),w(3); bfE=B(0) ----
    WLOAD(wfE, 0); WLOAD(wfO, 1);
    BLOAD(bfE);                       // chunk 0
    HCALC(pE, wfE); HWRITE(0, pE);
    HCALC(pO, wfO);
    WLOAD(wfE, 2); WLOAD(wfO, 3);
    __syncthreads();

    // ---- pairs p=0..13 ----
    for (int p = 0; p < 14; ++p) {
        BLOAD(bfO);                                   // B(2p+1)
        HWRITE(1, pO); HCALC(pE, wfE); WLOAD(wfE, 2 * p + 4);
        COMPUTE(0, bfE);                              // chunk 2p
        __syncthreads();
        BLOAD(bfE);                                   // B(2p+2)
        HWRITE(0, pE); HCALC(pO, wfO); WLOAD(wfO, 2 * p + 5);
        COMPUTE(1, bfO);                              // chunk 2p+1
        __syncthreads();
    }
    // ---- pair 14: chunks 28,29 (no wloads) ----
    BLOAD(bfO);                                       // B(29)
    HWRITE(1, pO); HCALC(pE, wfE);
    COMPUTE(0, bfE); __syncthreads();                 // chunk 28
    BLOAD(bfE);                                       // B(30)
    HWRITE(0, pE); HCALC(pO, wfO);
    COMPUTE(1, bfO); __syncthreads();                 // chunk 29
    // ---- tail: chunks 30,31 ----
    BLOAD(bfO);                                       // B(31)
    HWRITE(1, pO);
    COMPUTE(0, bfE); __syncthreads();                 // chunk 30
    COMPUTE(1, bfO);                                  // chunk 31

#undef COMPUTE
#undef HWRITE
#undef HCALC
#undef BLOAD
#undef WLOAD

    // ---- epilogue: + b2 (verbatim, harness-verified layout) ----
    float bb[4];
    #pragma unroll
    for (int nt = 0; nt < 4; ++nt) bb[nt] = b2[n0 + wn * 64 + nt * 16 + l16];
    #pragma unroll
    for (int mt = 0; mt < 4; ++mt) {
        const int mbase = m0 + wm * 64 + mt * 16 + quad * 4;
        #pragma unroll
        for (int nt = 0; nt < 4; ++nt) {
            const int n = n0 + wn * 64 + nt * 16 + l16;
            #pragma unroll
            for (int r = 0; r < 4; ++r)
                out[(size_t)(mbase + r) * EDIM + n] = acc[mt][nt][r] + bb[nt];
        }
    }
}

extern "C" void kernel_launch(void* const* d_in, const int* in_sizes, int n_in,
                              void* d_out, int out_size, void* d_ws, size_t ws_size,
                              hipStream_t stream) {
    const float* x  = (const float*)d_in[0];
    const float* rx = (const float*)d_in[1];
    const float* w1 = (const float*)d_in[2];
    const float* b1 = (const float*)d_in[3];
    const float* w2 = (const float*)d_in[4];
    const float* b2 = (const float*)d_in[5];
    float* out = (float*)d_out;

    const int M = in_sizes[0] / EDIM;   // 16384

    ushort* w2p = (ushort*)d_ws;                                    // 2 MiB
    ushort* w1t = (ushort*)((char*)d_ws + (size_t)EDIM * FDIM * 2); // 128 KiB
    (void)ws_size; (void)n_in; (void)out_size;

    hipLaunchKernelGGL(prep, dim3(256), dim3(256), 0, stream, w2, w1, b1, w2p, w1t);
    hipLaunchKernelGGL(fused, dim3(M / BM, EDIM / BN), dim3(256), 0, stream,
                       x, rx, w1t, w2p, b2, out);
}